// Round 6
// baseline (5652.827 us; speedup 1.0000x reference)
//
#include <hip/hip_runtime.h>
#include <math.h>

#define N_NODES  100000
#define N_EDGES  3200000
#define K_IN     1433
#define NH       16
#define NO       7

#define TK       16
#define KSPLIT   9
#define CPS      10                           // chunks per split (9*10*16 = 1440 >= 1433)
#define RW       (CPS * TK)                   // 160 W1 rows per split
#define RPT      2                            // rows per thread
#define TROWS    (64 * RPT)                   // 128 rows per wave-tile
#define NTILE2   ((N_NODES + TROWS - 1) / TROWS)  // 782
#define NRB2     ((NTILE2 + 3) / 4)               // 196 row-blocks (4 tiles/block)
#define SLOT     96                           // adjacency slots per node

typedef float f4  __attribute__((ext_vector_type(4)));
typedef float f4u __attribute__((ext_vector_type(4), aligned(4)));

// ---------------- K1: single-pass build (deg_out, deg_in/cursor, slotted adj) ----
__global__ __launch_bounds__(256)
void k_build(const int* __restrict__ src, const int* __restrict__ dst,
             int* __restrict__ deg_out, int* __restrict__ cnt,
             int* __restrict__ adj) {
    int i = blockIdx.x * blockDim.x + threadIdx.x;
    int stride = gridDim.x * blockDim.x;
    for (; i < N_EDGES; i += stride) {
        int s = src[i], d = dst[i];
        atomicAdd(&deg_out[s], 1);
        int p = atomicAdd(&cnt[d], 1);
        if (p < SLOT) adj[d * SLOT + p] = s;
    }
}

// ---------------- K2: hpart[split] = X[:, ksplit] @ W1[ksplit, :] ----------------
// No X-LDS: each thread owns 2 rows, keeps the chunk's x-values in registers
// (double-buffered, static indices under full unroll). W slice (160x16) staged
// in LDS once per block; inner loop reads it as wave-uniform ds_read_b128
// broadcasts, amortized over 2 rows/thread.
__global__ __launch_bounds__(256)
void k_gemm1(const float* __restrict__ X, const float* __restrict__ W1,
             float* __restrict__ hpart) {
    __shared__ float wlds[RW * NH];            // 10240 B = 640 f4
    const int wid = threadIdx.x >> 6;
    const int t   = threadIdx.x & 63;
    const int rb    = blockIdx.x % NRB2;
    const int split = blockIdx.x / NRB2;

    // ---- stage this split's W1 slice into LDS (zero-fill past K_IN) ----
    {
        const f4* W1v = (const f4*)W1;         // each W1 row = 4 f4
        const int wbase = split * RW;
#pragma unroll
        for (int r = 0; r < 3; ++r) {          // ceil(640/256) = 3 iters
            int idx = r * 256 + threadIdx.x;   // f4 index into wlds
            if (idx < RW * 4) {
                int krow = wbase + (idx >> 2);
                f4 wv = 0.f;
                if (krow < K_IN) wv = W1v[krow * 4 + (idx & 3)];
                ((f4*)wlds)[idx] = wv;
            }
        }
    }
    __syncthreads();

    const int tile = rb * 4 + wid;
    if (tile >= NTILE2) return;                // wave-uniform, after the sync
    const int base = tile * TROWS;
    const int r0 = min(base + t, N_NODES - 1);
    const int r1 = min(base + 64 + t, N_NODES - 1);
    const float* xr0 = X + (size_t)r0 * K_IN;
    const float* xr1 = X + (size_t)r1 * K_IN;

    f4 accA0 = 0.f, accA1 = 0.f, accA2 = 0.f, accA3 = 0.f;
    f4 accB0 = 0.f, accB1 = 0.f, accB2 = 0.f, accB3 = 0.f;

    const int c0 = split * CPS;
    f4 bufA[2][4], bufB[2][4];                 // [cc&1] is static after full unroll
    {
        const int k = c0 * TK;                 // <= 1280, vector-safe
#pragma unroll
        for (int i = 0; i < 4; ++i) {
            bufA[0][i] = *(const f4u*)(xr0 + k + 4 * i);
            bufB[0][i] = *(const f4u*)(xr1 + k + 4 * i);
        }
    }

#pragma unroll
    for (int cc = 0; cc < CPS; ++cc) {
        const int cur = cc & 1, nxt = cur ^ 1;
        // prefetch next chunk (in flight across this chunk's compute)
        if (cc + 1 < CPS) {
            const int kn = (c0 + cc + 1) * TK;
            if (kn + TK - 1 < K_IN) {          // wave-uniform; all but chunk 89
#pragma unroll
                for (int i = 0; i < 4; ++i) {
                    bufA[nxt][i] = *(const f4u*)(xr0 + kn + 4 * i);
                    bufB[nxt][i] = *(const f4u*)(xr1 + kn + 4 * i);
                }
            } else {
                // tail chunk (k=1424..1439): g0,g1 vector (<=1431); g2 scalar
                // elem0 (k=1432, last valid); g3 zero. W rows >=1433 are 0 in
                // LDS, so those x slots are dead.
                bufA[nxt][0] = *(const f4u*)(xr0 + kn);
                bufB[nxt][0] = *(const f4u*)(xr1 + kn);
                bufA[nxt][1] = *(const f4u*)(xr0 + kn + 4);
                bufB[nxt][1] = *(const f4u*)(xr1 + kn + 4);
                f4 za = 0.f, zb = 0.f;
                za[0] = xr0[kn + 8];
                zb[0] = xr1[kn + 8];
                bufA[nxt][2] = za;  bufB[nxt][2] = zb;
                bufA[nxt][3] = 0.f; bufB[nxt][3] = 0.f;
            }
        }
        // compute chunk cc from registers + W broadcasts
#pragma unroll
        for (int kk = 0; kk < TK; ++kk) {
            const float xa = bufA[cur][kk >> 2][kk & 3];
            const float xb = bufB[cur][kk >> 2][kk & 3];
            const f4* wr = (const f4*)(wlds + (cc * TK + kk) * NH);
            accA0 += xa * wr[0]; accA1 += xa * wr[1];
            accA2 += xa * wr[2]; accA3 += xa * wr[3];
            accB0 += xb * wr[0]; accB1 += xb * wr[1];
            accB2 += xb * wr[2]; accB3 += xb * wr[3];
        }
    }

    if (base + t < N_NODES) {
        f4* hp = (f4*)(hpart + ((size_t)split * N_NODES + r0) * NH);
        hp[0] = accA0; hp[1] = accA1; hp[2] = accA2; hp[3] = accA3;
    }
    if (base + 64 + t < N_NODES) {
        f4* hp = (f4*)(hpart + ((size_t)split * N_NODES + r1) * NH);
        hp[0] = accB0; hp[1] = accB1; hp[2] = accB2; hp[3] = accB3;
    }
}

// ---------------- K3: h = norm_src * sum_s hpart[s] ----------------
__global__ __launch_bounds__(256)
void k_reduce(const float* __restrict__ hpart, const int* __restrict__ deg_out,
              float* __restrict__ h) {
    int idx = blockIdx.x * 256 + threadIdx.x;   // f4 index
    if (idx >= N_NODES * 4) return;
    f4 a = 0.f;
#pragma unroll
    for (int s = 0; s < KSPLIT; ++s)
        a += ((const f4*)hpart)[(size_t)s * N_NODES * 4 + idx];
    float ns = rsqrtf((float)max(deg_out[idx >> 2], 1));
    ((f4*)h)[idx] = a * ns;
}

// ---------------- K4: gather layer1 + relu + fused (.. @ W2) ----------------
__global__ __launch_bounds__(256)
void k_layer1(const float* __restrict__ h, const int* __restrict__ adj,
              const int* __restrict__ cnt, const int* __restrict__ deg_out,
              const float* __restrict__ W2, const float* __restrict__ b1,
              float* __restrict__ g) {
    const int lane = threadIdx.x & 63;
    const int wid  = threadIdx.x >> 6;
    const int d    = blockIdx.x * 4 + wid;
    if (d >= N_NODES) return;                  // wave-uniform
    const int j4 = lane & 3, slot = lane >> 2;
    const int start = d * SLOT;
    const int deg   = min(cnt[d], SLOT);
    const int end   = start + deg;
    f4 agg = 0.f;
    for (int p = start + slot; p < end; p += 16) {
        int s = adj[p];
        agg += ((const f4*)h)[s * 4 + j4];
    }
#pragma unroll
    for (int off = 4; off < 64; off <<= 1) {
        agg[0] += __shfl_xor(agg[0], off);
        agg[1] += __shfl_xor(agg[1], off);
        agg[2] += __shfl_xor(agg[2], off);
        agg[3] += __shfl_xor(agg[3], off);
    }
    __shared__ float st[4][NH];
    const float nd = rsqrtf((float)max(deg, 1));
    if (slot == 0) {
        f4 bb = ((const f4*)b1)[j4];
        f4 tj;
        tj[0] = fmaxf(fmaf(agg[0], nd, bb[0]), 0.f);
        tj[1] = fmaxf(fmaf(agg[1], nd, bb[1]), 0.f);
        tj[2] = fmaxf(fmaf(agg[2], nd, bb[2]), 0.f);
        tj[3] = fmaxf(fmaf(agg[3], nd, bb[3]), 0.f);
        ((f4*)st[wid])[j4] = tj;
    }
    __builtin_amdgcn_wave_barrier();
    float r = 0.f;
    if (lane < NO) {
#pragma unroll
        for (int qq = 0; qq < NH; ++qq)
            r = fmaf(st[wid][qq], W2[qq * NO + lane], r);
    }
    if (lane < 8) {
        float ns = rsqrtf((float)max(deg_out[d], 1));
        g[(size_t)d * 8 + lane] = (lane < NO) ? ns * r : 0.f;  // zero pad slot
    }
}

// ---------------- K5: gather layer2 -> out ----------------
__global__ __launch_bounds__(256)
void k_layer2(const float* __restrict__ g, const int* __restrict__ adj,
              const int* __restrict__ cnt, const float* __restrict__ b2,
              float* __restrict__ out) {
    const int lane = threadIdx.x & 63;
    const int wid  = threadIdx.x >> 6;
    const int d    = blockIdx.x * 4 + wid;
    if (d >= N_NODES) return;
    const int o4 = lane & 1, slot = lane >> 1;
    const int start = d * SLOT;
    const int deg   = min(cnt[d], SLOT);
    const int end   = start + deg;
    f4 agg = 0.f;
    for (int p = start + slot; p < end; p += 32) {
        int s = adj[p];
        agg += ((const f4*)g)[s * 2 + o4];
    }
#pragma unroll
    for (int off = 2; off < 64; off <<= 1) {
        agg[0] += __shfl_xor(agg[0], off);
        agg[1] += __shfl_xor(agg[1], off);
        agg[2] += __shfl_xor(agg[2], off);
        agg[3] += __shfl_xor(agg[3], off);
    }
    // even lanes hold o=0..3 sums, odd lanes hold o=4..7 sums
    const int sl = lane >> 2;
    float v0 = __shfl(agg[0], sl);
    float v1 = __shfl(agg[1], sl);
    float v2 = __shfl(agg[2], sl);
    float v3 = __shfl(agg[3], sl);
    int cm = lane & 3;
    float v = (cm == 0) ? v0 : (cm == 1) ? v1 : (cm == 2) ? v2 : v3;
    if (lane < NO) {
        float nd = rsqrtf((float)max(deg, 1));
        out[(size_t)d * NO + lane] = fmaf(v, nd, b2[lane]);
    }
}

extern "C" void kernel_launch(void* const* d_in, const int* in_sizes, int n_in,
                              void* d_out, int out_size, void* d_ws, size_t ws_size,
                              hipStream_t stream) {
    const float* X   = (const float*)d_in[0];
    const int*   src = (const int*)d_in[1];
    const int*   dst = (const int*)d_in[2];
    const float* W1  = (const float*)d_in[3];
    const float* b1  = (const float*)d_in[4];
    const float* W2  = (const float*)d_in[5];
    const float* b2  = (const float*)d_in[6];
    float* out = (float*)d_out;

    char* w = (char*)d_ws;
    float* hpart    = (float*)w;  w += (size_t)KSPLIT * N_NODES * NH * 4; // 57.6 MB
    float* h        = (float*)w;  w += (size_t)N_NODES * NH * 4;          // 6.4 MB
    float* g        = (float*)w;  w += (size_t)N_NODES * 8 * 4;           // 3.2 MB
    int*   adj      = (int*)w;    w += (size_t)N_NODES * SLOT * 4;        // 38.4 MB
    int*   deg_out_a= (int*)w;    w += (size_t)N_NODES * 4;
    int*   cnt      = (int*)w;    w += (size_t)N_NODES * 4;

    hipMemsetAsync(deg_out_a, 0, (size_t)N_NODES * 2 * 4, stream);

    k_build <<<2048, 256, 0, stream>>>(src, dst, deg_out_a, cnt, adj);
    k_gemm1 <<<NRB2 * KSPLIT, 256, 0, stream>>>(X, W1, hpart);
    k_reduce<<<(N_NODES * 4 + 255) / 256, 256, 0, stream>>>(hpart, deg_out_a, h);
    k_layer1<<<(N_NODES + 3) / 4, 256, 0, stream>>>(h, adj, cnt, deg_out_a,
                                                    W2, b1, g);
    k_layer2<<<(N_NODES + 3) / 4, 256, 0, stream>>>(g, adj, cnt, b2, out);
}

// Round 7
// 5559.074 us; speedup vs baseline: 1.0169x; 1.0169x over previous
//
#include <hip/hip_runtime.h>
#include <math.h>

#define N_NODES  100000
#define N_EDGES  3200000
#define K_IN     1433
#define NH       16
#define NO       7

#define TK       16
#define KSPLIT   9
#define CPS      10                           // chunks per split (9*10*16 = 1440 >= 1433)
#define RW       (CPS * TK)                   // 160 W1 rows per split
#define RPT      2                            // rows per thread
#define TROWS    (64 * RPT)                   // 128 rows per wave-tile
#define NTILE2   ((N_NODES + TROWS - 1) / TROWS)  // 782
#define NRB2     ((NTILE2 + 3) / 4)               // 196 row-blocks (4 tiles/block)
#define SLOT     96                           // adjacency slots per node

typedef float f4  __attribute__((ext_vector_type(4)));
typedef float f4u __attribute__((ext_vector_type(4), aligned(4)));

// ---------------- K1: single-pass build (deg_out, deg_in/cursor, slotted adj) ----
__global__ __launch_bounds__(256)
void k_build(const int* __restrict__ src, const int* __restrict__ dst,
             int* __restrict__ deg_out, int* __restrict__ cnt,
             int* __restrict__ adj) {
    int i = blockIdx.x * blockDim.x + threadIdx.x;
    int stride = gridDim.x * blockDim.x;
    for (; i < N_EDGES; i += stride) {
        int s = src[i], d = dst[i];
        atomicAdd(&deg_out[s], 1);
        int p = atomicAdd(&cnt[d], 1);
        if (p < SLOT) adj[d * SLOT + p] = s;
    }
}

// ---------------- K2: hpart[split] = X[:, ksplit] @ W1[ksplit, :] ----------------
// X kept in NAMED register buffers (no runtime-indexed arrays -> no scratch,
// rule #20). Manual 2x unroll: even chunk computes from x-set while y-set
// prefetches, odd chunk vice versa. W slice staged in LDS once per block,
// read as wave-uniform ds_read_b128 broadcasts amortized over 2 rows/thread.

// full 16-k chunk load into one buffer set
#define LOAD_FULL(KN, A0,A1,A2,A3, B0,B1,B2,B3)            \
  { A0 = *(const f4u*)(xr0 + (KN));                        \
    B0 = *(const f4u*)(xr1 + (KN));                        \
    A1 = *(const f4u*)(xr0 + (KN) + 4);                    \
    B1 = *(const f4u*)(xr1 + (KN) + 4);                    \
    A2 = *(const f4u*)(xr0 + (KN) + 8);                    \
    B2 = *(const f4u*)(xr1 + (KN) + 8);                    \
    A3 = *(const f4u*)(xr0 + (KN) + 12);                   \
    B3 = *(const f4u*)(xr1 + (KN) + 12); }

// tail chunk (k=1424..1439): last valid k is 1432; W rows >=1433 are zero in
// LDS so the zeroed x slots are dead anyway.
#define LOAD_TAIL(KN, A0,A1,A2,A3, B0,B1,B2,B3)            \
  { A0 = *(const f4u*)(xr0 + (KN));                        \
    B0 = *(const f4u*)(xr1 + (KN));                        \
    A1 = *(const f4u*)(xr0 + (KN) + 4);                    \
    B1 = *(const f4u*)(xr1 + (KN) + 4);                    \
    A2 = 0.f; B2 = 0.f;                                    \
    A2[0] = xr0[(KN) + 8]; B2[0] = xr1[(KN) + 8];          \
    A3 = 0.f; B3 = 0.f; }

#define LOAD_CHUNK(KN, A0,A1,A2,A3, B0,B1,B2,B3)           \
  { if ((KN) + TK <= K_IN) { LOAD_FULL(KN, A0,A1,A2,A3, B0,B1,B2,B3) } \
    else                   { LOAD_TAIL(KN, A0,A1,A2,A3, B0,B1,B2,B3) } }

// compute one chunk; CC is a compile-time constant, kk-selects fold statically
#define CHUNK_FMA(CC, A0,A1,A2,A3, B0,B1,B2,B3)                         \
  { _Pragma("unroll")                                                   \
    for (int kk = 0; kk < TK; ++kk) {                                   \
      const f4 va = (kk < 4) ? A0 : (kk < 8) ? A1 : (kk < 12) ? A2 : A3;\
      const f4 vb = (kk < 4) ? B0 : (kk < 8) ? B1 : (kk < 12) ? B2 : B3;\
      const float xa = va[kk & 3], xb = vb[kk & 3];                     \
      const f4* wr = (const f4*)(wlds + ((CC) * TK + kk) * NH);         \
      accA0 += xa * wr[0]; accA1 += xa * wr[1];                         \
      accA2 += xa * wr[2]; accA3 += xa * wr[3];                         \
      accB0 += xb * wr[0]; accB1 += xb * wr[1];                         \
      accB2 += xb * wr[2]; accB3 += xb * wr[3];                         \
    } }

__global__ __launch_bounds__(256)
void k_gemm1(const float* __restrict__ X, const float* __restrict__ W1,
             float* __restrict__ hpart) {
    __shared__ float wlds[RW * NH];            // 10240 B = 640 f4
    const int wid = threadIdx.x >> 6;
    const int t   = threadIdx.x & 63;
    const int rb    = blockIdx.x % NRB2;
    const int split = blockIdx.x / NRB2;

    // ---- stage this split's W1 slice into LDS (zero-fill past K_IN) ----
    {
        const f4* W1v = (const f4*)W1;         // each W1 row = 4 f4
        const int wbase = split * RW;
#pragma unroll
        for (int r = 0; r < 3; ++r) {          // ceil(640/256) = 3 iters
            int idx = r * 256 + threadIdx.x;   // f4 index into wlds
            if (idx < RW * 4) {
                int krow = wbase + (idx >> 2);
                f4 wv = 0.f;
                if (krow < K_IN) wv = W1v[krow * 4 + (idx & 3)];
                ((f4*)wlds)[idx] = wv;
            }
        }
    }
    __syncthreads();

    const int tile = rb * 4 + wid;
    if (tile >= NTILE2) return;                // wave-uniform, after the sync
    const int base = tile * TROWS;
    const int r0 = min(base + t, N_NODES - 1);
    const int r1 = min(base + 64 + t, N_NODES - 1);
    const float* xr0 = X + (size_t)r0 * K_IN;
    const float* xr1 = X + (size_t)r1 * K_IN;

    f4 accA0 = 0.f, accA1 = 0.f, accA2 = 0.f, accA3 = 0.f;
    f4 accB0 = 0.f, accB1 = 0.f, accB2 = 0.f, accB3 = 0.f;

    // named double-buffer sets (x = even chunks, y = odd chunks)
    f4 xA0, xA1, xA2, xA3, xB0, xB1, xB2, xB3;
    f4 yA0, yA1, yA2, yA3, yB0, yB1, yB2, yB3;

    const int c0 = split * CPS;
    // prologue: chunk c0 into x-set (k <= 1280+15, always full)
    LOAD_FULL(c0 * TK, xA0, xA1, xA2, xA3, xB0, xB1, xB2, xB3)

#pragma unroll
    for (int j = 0; j < CPS / 2; ++j) {
        // even chunk 2j: prefetch 2j+1 into y, compute from x
        LOAD_CHUNK((c0 + 2 * j + 1) * TK, yA0, yA1, yA2, yA3, yB0, yB1, yB2, yB3)
        CHUNK_FMA(2 * j, xA0, xA1, xA2, xA3, xB0, xB1, xB2, xB3)
        // odd chunk 2j+1: prefetch 2j+2 into x (if any), compute from y
        if (2 * j + 2 < CPS) {
            LOAD_CHUNK((c0 + 2 * j + 2) * TK, xA0, xA1, xA2, xA3, xB0, xB1, xB2, xB3)
        }
        CHUNK_FMA(2 * j + 1, yA0, yA1, yA2, yA3, yB0, yB1, yB2, yB3)
    }

    if (base + t < N_NODES) {
        f4* hp = (f4*)(hpart + ((size_t)split * N_NODES + r0) * NH);
        hp[0] = accA0; hp[1] = accA1; hp[2] = accA2; hp[3] = accA3;
    }
    if (base + 64 + t < N_NODES) {
        f4* hp = (f4*)(hpart + ((size_t)split * N_NODES + r1) * NH);
        hp[0] = accB0; hp[1] = accB1; hp[2] = accB2; hp[3] = accB3;
    }
}

// ---------------- K3: h = norm_src * sum_s hpart[s] ----------------
__global__ __launch_bounds__(256)
void k_reduce(const float* __restrict__ hpart, const int* __restrict__ deg_out,
              float* __restrict__ h) {
    int idx = blockIdx.x * 256 + threadIdx.x;   // f4 index
    if (idx >= N_NODES * 4) return;
    f4 a = 0.f;
#pragma unroll
    for (int s = 0; s < KSPLIT; ++s)
        a += ((const f4*)hpart)[(size_t)s * N_NODES * 4 + idx];
    float ns = rsqrtf((float)max(deg_out[idx >> 2], 1));
    ((f4*)h)[idx] = a * ns;
}

// ---------------- K4: gather layer1 + relu + fused (.. @ W2) ----------------
__global__ __launch_bounds__(256)
void k_layer1(const float* __restrict__ h, const int* __restrict__ adj,
              const int* __restrict__ cnt, const int* __restrict__ deg_out,
              const float* __restrict__ W2, const float* __restrict__ b1,
              float* __restrict__ g) {
    const int lane = threadIdx.x & 63;
    const int wid  = threadIdx.x >> 6;
    const int d    = blockIdx.x * 4 + wid;
    if (d >= N_NODES) return;                  // wave-uniform
    const int j4 = lane & 3, slot = lane >> 2;
    const int start = d * SLOT;
    const int deg   = min(cnt[d], SLOT);
    const int end   = start + deg;
    f4 agg = 0.f;
    for (int p = start + slot; p < end; p += 16) {
        int s = adj[p];
        agg += ((const f4*)h)[s * 4 + j4];
    }
#pragma unroll
    for (int off = 4; off < 64; off <<= 1) {
        agg[0] += __shfl_xor(agg[0], off);
        agg[1] += __shfl_xor(agg[1], off);
        agg[2] += __shfl_xor(agg[2], off);
        agg[3] += __shfl_xor(agg[3], off);
    }
    __shared__ float st[4][NH];
    const float nd = rsqrtf((float)max(deg, 1));
    if (slot == 0) {
        f4 bb = ((const f4*)b1)[j4];
        f4 tj;
        tj[0] = fmaxf(fmaf(agg[0], nd, bb[0]), 0.f);
        tj[1] = fmaxf(fmaf(agg[1], nd, bb[1]), 0.f);
        tj[2] = fmaxf(fmaf(agg[2], nd, bb[2]), 0.f);
        tj[3] = fmaxf(fmaf(agg[3], nd, bb[3]), 0.f);
        ((f4*)st[wid])[j4] = tj;
    }
    __builtin_amdgcn_wave_barrier();
    float r = 0.f;
    if (lane < NO) {
#pragma unroll
        for (int qq = 0; qq < NH; ++qq)
            r = fmaf(st[wid][qq], W2[qq * NO + lane], r);
    }
    if (lane < 8) {
        float ns = rsqrtf((float)max(deg_out[d], 1));
        g[(size_t)d * 8 + lane] = (lane < NO) ? ns * r : 0.f;  // zero pad slot
    }
}

// ---------------- K5: gather layer2 -> out ----------------
__global__ __launch_bounds__(256)
void k_layer2(const float* __restrict__ g, const int* __restrict__ adj,
              const int* __restrict__ cnt, const float* __restrict__ b2,
              float* __restrict__ out) {
    const int lane = threadIdx.x & 63;
    const int wid  = threadIdx.x >> 6;
    const int d    = blockIdx.x * 4 + wid;
    if (d >= N_NODES) return;
    const int o4 = lane & 1, slot = lane >> 1;
    const int start = d * SLOT;
    const int deg   = min(cnt[d], SLOT);
    const int end   = start + deg;
    f4 agg = 0.f;
    for (int p = start + slot; p < end; p += 32) {
        int s = adj[p];
        agg += ((const f4*)g)[s * 2 + o4];
    }
#pragma unroll
    for (int off = 2; off < 64; off <<= 1) {
        agg[0] += __shfl_xor(agg[0], off);
        agg[1] += __shfl_xor(agg[1], off);
        agg[2] += __shfl_xor(agg[2], off);
        agg[3] += __shfl_xor(agg[3], off);
    }
    // even lanes hold o=0..3 sums, odd lanes hold o=4..7 sums
    const int sl = lane >> 2;
    float v0 = __shfl(agg[0], sl);
    float v1 = __shfl(agg[1], sl);
    float v2 = __shfl(agg[2], sl);
    float v3 = __shfl(agg[3], sl);
    int cm = lane & 3;
    float v = (cm == 0) ? v0 : (cm == 1) ? v1 : (cm == 2) ? v2 : v3;
    if (lane < NO) {
        float nd = rsqrtf((float)max(deg, 1));
        out[(size_t)d * NO + lane] = fmaf(v, nd, b2[lane]);
    }
}

extern "C" void kernel_launch(void* const* d_in, const int* in_sizes, int n_in,
                              void* d_out, int out_size, void* d_ws, size_t ws_size,
                              hipStream_t stream) {
    const float* X   = (const float*)d_in[0];
    const int*   src = (const int*)d_in[1];
    const int*   dst = (const int*)d_in[2];
    const float* W1  = (const float*)d_in[3];
    const float* b1  = (const float*)d_in[4];
    const float* W2  = (const float*)d_in[5];
    const float* b2  = (const float*)d_in[6];
    float* out = (float*)d_out;

    char* w = (char*)d_ws;
    float* hpart    = (float*)w;  w += (size_t)KSPLIT * N_NODES * NH * 4; // 57.6 MB
    float* h        = (float*)w;  w += (size_t)N_NODES * NH * 4;          // 6.4 MB
    float* g        = (float*)w;  w += (size_t)N_NODES * 8 * 4;           // 3.2 MB
    int*   adj      = (int*)w;    w += (size_t)N_NODES * SLOT * 4;        // 38.4 MB
    int*   deg_out_a= (int*)w;    w += (size_t)N_NODES * 4;
    int*   cnt      = (int*)w;    w += (size_t)N_NODES * 4;

    hipMemsetAsync(deg_out_a, 0, (size_t)N_NODES * 2 * 4, stream);

    k_build <<<2048, 256, 0, stream>>>(src, dst, deg_out_a, cnt, adj);
    k_gemm1 <<<NRB2 * KSPLIT, 256, 0, stream>>>(X, W1, hpart);
    k_reduce<<<(N_NODES * 4 + 255) / 256, 256, 0, stream>>>(hpart, deg_out_a, h);
    k_layer1<<<(N_NODES + 3) / 4, 256, 0, stream>>>(h, adj, cnt, deg_out_a,
                                                    W2, b1, g);
    k_layer2<<<(N_NODES + 3) / 4, 256, 0, stream>>>(g, adj, cnt, b2, out);
}

// Round 8
// 612.133 us; speedup vs baseline: 9.2346x; 9.0815x over previous
//
#include <hip/hip_runtime.h>
#include <math.h>

#define N_NODES  100000
#define N_EDGES  3200000
#define K_IN     1433
#define NH       16
#define NO       7

#define TK       16
#define KSPLIT   9
#define CPS      10                           // chunks per split (9*10*16 = 1440 >= 1433)
#define RW       (CPS * TK)                   // 160 W1 rows per split
#define RPT      2                            // rows per thread
#define TROWS    (64 * RPT)                   // 128 rows per wave-tile
#define NTILE2   ((N_NODES + TROWS - 1) / TROWS)  // 782
#define NRB2     ((NTILE2 + 3) / 4)               // 196 row-blocks (4 tiles/block)
#define SLOT     96                           // adjacency slots per node

typedef float f4  __attribute__((ext_vector_type(4)));
typedef float f4u __attribute__((ext_vector_type(4), aligned(4)));

// ---------------- K1: single-pass build (deg_out, deg_in/cursor, slotted adj) ----
__global__ __launch_bounds__(256)
void k_build(const int* __restrict__ src, const int* __restrict__ dst,
             int* __restrict__ deg_out, int* __restrict__ cnt,
             int* __restrict__ adj) {
    int i = blockIdx.x * blockDim.x + threadIdx.x;
    int stride = gridDim.x * blockDim.x;
    for (; i < N_EDGES; i += stride) {
        int s = src[i], d = dst[i];
        atomicAdd(&deg_out[s], 1);
        int p = atomicAdd(&cnt[d], 1);
        if (p < SLOT) adj[d * SLOT + p] = s;
    }
}

// ---------------- K2: hpart[split] = X[:, ksplit] @ W1[ksplit, :] ----------------
// RPT=2 rows/thread in registers; W slice in LDS (wave-uniform ds_read_b128
// broadcasts). Chunk loop is ROLLED (#pragma unroll 1): full unroll let the
// scheduler hoist ~80 loads -> 256 VGPR + scratch spill (R6/R7). Rolled loop
// with named x/y double-buffer sets bounds live loads to one prefetch set.

#define LOAD_FULL(KN, A0,A1,A2,A3, B0,B1,B2,B3)            \
  { A0 = *(const f4u*)(xr0 + (KN));                        \
    B0 = *(const f4u*)(xr1 + (KN));                        \
    A1 = *(const f4u*)(xr0 + (KN) + 4);                    \
    B1 = *(const f4u*)(xr1 + (KN) + 4);                    \
    A2 = *(const f4u*)(xr0 + (KN) + 8);                    \
    B2 = *(const f4u*)(xr1 + (KN) + 8);                    \
    A3 = *(const f4u*)(xr0 + (KN) + 12);                   \
    B3 = *(const f4u*)(xr1 + (KN) + 12); }

// tail chunk (k=1424..1439): last valid k is 1432; W rows >=1433 are zero in
// LDS so the zeroed x slots are dead anyway.
#define LOAD_TAIL(KN, A0,A1,A2,A3, B0,B1,B2,B3)            \
  { A0 = *(const f4u*)(xr0 + (KN));                        \
    B0 = *(const f4u*)(xr1 + (KN));                        \
    A1 = *(const f4u*)(xr0 + (KN) + 4);                    \
    B1 = *(const f4u*)(xr1 + (KN) + 4);                    \
    A2 = 0.f; B2 = 0.f;                                    \
    A2[0] = xr0[(KN) + 8]; B2[0] = xr1[(KN) + 8];          \
    A3 = 0.f; B3 = 0.f; }

#define LOAD_CHUNK(KN, A0,A1,A2,A3, B0,B1,B2,B3)           \
  { if ((KN) + TK <= K_IN) { LOAD_FULL(KN, A0,A1,A2,A3, B0,B1,B2,B3) } \
    else                   { LOAD_TAIL(KN, A0,A1,A2,A3, B0,B1,B2,B3) } }

// CC may be runtime (LDS base addr in a register); kk-selects fold statically.
#define CHUNK_FMA(CC, A0,A1,A2,A3, B0,B1,B2,B3)                         \
  { const float* wbase = wlds + (CC) * (TK * NH);                       \
    _Pragma("unroll")                                                   \
    for (int kk = 0; kk < TK; ++kk) {                                   \
      const f4 va = (kk < 4) ? A0 : (kk < 8) ? A1 : (kk < 12) ? A2 : A3;\
      const f4 vb = (kk < 4) ? B0 : (kk < 8) ? B1 : (kk < 12) ? B2 : B3;\
      const float xa = va[kk & 3], xb = vb[kk & 3];                     \
      const f4* wr = (const f4*)(wbase + kk * NH);                      \
      accA0 += xa * wr[0]; accA1 += xa * wr[1];                         \
      accA2 += xa * wr[2]; accA3 += xa * wr[3];                         \
      accB0 += xb * wr[0]; accB1 += xb * wr[1];                         \
      accB2 += xb * wr[2]; accB3 += xb * wr[3];                         \
    } }

__global__ __launch_bounds__(256)
void k_gemm1(const float* __restrict__ X, const float* __restrict__ W1,
             float* __restrict__ hpart) {
    __shared__ float wlds[RW * NH];            // 10240 B = 640 f4
    const int wid = threadIdx.x >> 6;
    const int t   = threadIdx.x & 63;
    const int rb    = blockIdx.x % NRB2;
    const int split = blockIdx.x / NRB2;

    // ---- stage this split's W1 slice into LDS (zero-fill past K_IN) ----
    {
        const f4* W1v = (const f4*)W1;         // each W1 row = 4 f4
        const int wbase = split * RW;
#pragma unroll
        for (int r = 0; r < 3; ++r) {          // ceil(640/256) = 3 iters
            int idx = r * 256 + threadIdx.x;   // f4 index into wlds
            if (idx < RW * 4) {
                int krow = wbase + (idx >> 2);
                f4 wv = 0.f;
                if (krow < K_IN) wv = W1v[krow * 4 + (idx & 3)];
                ((f4*)wlds)[idx] = wv;
            }
        }
    }
    __syncthreads();

    const int tile = rb * 4 + wid;
    if (tile >= NTILE2) return;                // wave-uniform, after the sync
    const int base = tile * TROWS;
    const int r0 = min(base + t, N_NODES - 1);
    const int r1 = min(base + 64 + t, N_NODES - 1);
    const float* xr0 = X + (size_t)r0 * K_IN;
    const float* xr1 = X + (size_t)r1 * K_IN;

    f4 accA0 = 0.f, accA1 = 0.f, accA2 = 0.f, accA3 = 0.f;
    f4 accB0 = 0.f, accB1 = 0.f, accB2 = 0.f, accB3 = 0.f;

    // named double-buffer sets (x = even chunks, y = odd chunks)
    f4 xA0, xA1, xA2, xA3, xB0, xB1, xB2, xB3;
    f4 yA0, yA1, yA2, yA3, yB0, yB1, yB2, yB3;

    const int c0 = split * CPS;
    // prologue: chunk c0 into x-set (k0 <= 1280, always full)
    LOAD_FULL(c0 * TK, xA0, xA1, xA2, xA3, xB0, xB1, xB2, xB3)

#pragma unroll 1
    for (int j = 0; j < CPS / 2; ++j) {
        const int ce = 2 * j;                  // even chunk index within split
        // prefetch odd chunk into y (tail possible only at split 8, chunk 89)
        LOAD_CHUNK((c0 + ce + 1) * TK, yA0, yA1, yA2, yA3, yB0, yB1, yB2, yB3)
        CHUNK_FMA(ce, xA0, xA1, xA2, xA3, xB0, xB1, xB2, xB3)
        // prefetch next even chunk into x (max k0 = 88*16 = 1408: always full)
        if (j + 1 < CPS / 2) {
            LOAD_FULL((c0 + ce + 2) * TK, xA0, xA1, xA2, xA3, xB0, xB1, xB2, xB3)
        }
        CHUNK_FMA(ce + 1, yA0, yA1, yA2, yA3, yB0, yB1, yB2, yB3)
    }

    if (base + t < N_NODES) {
        f4* hp = (f4*)(hpart + ((size_t)split * N_NODES + r0) * NH);
        hp[0] = accA0; hp[1] = accA1; hp[2] = accA2; hp[3] = accA3;
    }
    if (base + 64 + t < N_NODES) {
        f4* hp = (f4*)(hpart + ((size_t)split * N_NODES + r1) * NH);
        hp[0] = accB0; hp[1] = accB1; hp[2] = accB2; hp[3] = accB3;
    }
}

// ---------------- K3: h = norm_src * sum_s hpart[s] ----------------
__global__ __launch_bounds__(256)
void k_reduce(const float* __restrict__ hpart, const int* __restrict__ deg_out,
              float* __restrict__ h) {
    int idx = blockIdx.x * 256 + threadIdx.x;   // f4 index
    if (idx >= N_NODES * 4) return;
    f4 a = 0.f;
#pragma unroll
    for (int s = 0; s < KSPLIT; ++s)
        a += ((const f4*)hpart)[(size_t)s * N_NODES * 4 + idx];
    float ns = rsqrtf((float)max(deg_out[idx >> 2], 1));
    ((f4*)h)[idx] = a * ns;
}

// ---------------- K4: gather layer1 + relu + fused (.. @ W2) ----------------
__global__ __launch_bounds__(256)
void k_layer1(const float* __restrict__ h, const int* __restrict__ adj,
              const int* __restrict__ cnt, const int* __restrict__ deg_out,
              const float* __restrict__ W2, const float* __restrict__ b1,
              float* __restrict__ g) {
    const int lane = threadIdx.x & 63;
    const int wid  = threadIdx.x >> 6;
    const int d    = blockIdx.x * 4 + wid;
    if (d >= N_NODES) return;                  // wave-uniform
    const int j4 = lane & 3, slot = lane >> 2;
    const int start = d * SLOT;
    const int deg   = min(cnt[d], SLOT);
    const int end   = start + deg;
    f4 agg = 0.f;
    for (int p = start + slot; p < end; p += 16) {
        int s = adj[p];
        agg += ((const f4*)h)[s * 4 + j4];
    }
#pragma unroll
    for (int off = 4; off < 64; off <<= 1) {
        agg[0] += __shfl_xor(agg[0], off);
        agg[1] += __shfl_xor(agg[1], off);
        agg[2] += __shfl_xor(agg[2], off);
        agg[3] += __shfl_xor(agg[3], off);
    }
    __shared__ float st[4][NH];
    const float nd = rsqrtf((float)max(deg, 1));
    if (slot == 0) {
        f4 bb = ((const f4*)b1)[j4];
        f4 tj;
        tj[0] = fmaxf(fmaf(agg[0], nd, bb[0]), 0.f);
        tj[1] = fmaxf(fmaf(agg[1], nd, bb[1]), 0.f);
        tj[2] = fmaxf(fmaf(agg[2], nd, bb[2]), 0.f);
        tj[3] = fmaxf(fmaf(agg[3], nd, bb[3]), 0.f);
        ((f4*)st[wid])[j4] = tj;
    }
    __builtin_amdgcn_wave_barrier();
    float r = 0.f;
    if (lane < NO) {
#pragma unroll
        for (int qq = 0; qq < NH; ++qq)
            r = fmaf(st[wid][qq], W2[qq * NO + lane], r);
    }
    if (lane < 8) {
        float ns = rsqrtf((float)max(deg_out[d], 1));
        g[(size_t)d * 8 + lane] = (lane < NO) ? ns * r : 0.f;  // zero pad slot
    }
}

// ---------------- K5: gather layer2 -> out ----------------
__global__ __launch_bounds__(256)
void k_layer2(const float* __restrict__ g, const int* __restrict__ adj,
              const int* __restrict__ cnt, const float* __restrict__ b2,
              float* __restrict__ out) {
    const int lane = threadIdx.x & 63;
    const int wid  = threadIdx.x >> 6;
    const int d    = blockIdx.x * 4 + wid;
    if (d >= N_NODES) return;
    const int o4 = lane & 1, slot = lane >> 1;
    const int start = d * SLOT;
    const int deg   = min(cnt[d], SLOT);
    const int end   = start + deg;
    f4 agg = 0.f;
    for (int p = start + slot; p < end; p += 32) {
        int s = adj[p];
        agg += ((const f4*)g)[s * 2 + o4];
    }
#pragma unroll
    for (int off = 2; off < 64; off <<= 1) {
        agg[0] += __shfl_xor(agg[0], off);
        agg[1] += __shfl_xor(agg[1], off);
        agg[2] += __shfl_xor(agg[2], off);
        agg[3] += __shfl_xor(agg[3], off);
    }
    // even lanes hold o=0..3 sums, odd lanes hold o=4..7 sums
    const int sl = lane >> 2;
    float v0 = __shfl(agg[0], sl);
    float v1 = __shfl(agg[1], sl);
    float v2 = __shfl(agg[2], sl);
    float v3 = __shfl(agg[3], sl);
    int cm = lane & 3;
    float v = (cm == 0) ? v0 : (cm == 1) ? v1 : (cm == 2) ? v2 : v3;
    if (lane < NO) {
        float nd = rsqrtf((float)max(deg, 1));
        out[(size_t)d * NO + lane] = fmaf(v, nd, b2[lane]);
    }
}

extern "C" void kernel_launch(void* const* d_in, const int* in_sizes, int n_in,
                              void* d_out, int out_size, void* d_ws, size_t ws_size,
                              hipStream_t stream) {
    const float* X   = (const float*)d_in[0];
    const int*   src = (const int*)d_in[1];
    const int*   dst = (const int*)d_in[2];
    const float* W1  = (const float*)d_in[3];
    const float* b1  = (const float*)d_in[4];
    const float* W2  = (const float*)d_in[5];
    const float* b2  = (const float*)d_in[6];
    float* out = (float*)d_out;

    char* w = (char*)d_ws;
    float* hpart    = (float*)w;  w += (size_t)KSPLIT * N_NODES * NH * 4; // 57.6 MB
    float* h        = (float*)w;  w += (size_t)N_NODES * NH * 4;          // 6.4 MB
    float* g        = (float*)w;  w += (size_t)N_NODES * 8 * 4;           // 3.2 MB
    int*   adj      = (int*)w;    w += (size_t)N_NODES * SLOT * 4;        // 38.4 MB
    int*   deg_out_a= (int*)w;    w += (size_t)N_NODES * 4;
    int*   cnt      = (int*)w;    w += (size_t)N_NODES * 4;

    hipMemsetAsync(deg_out_a, 0, (size_t)N_NODES * 2 * 4, stream);

    k_build <<<2048, 256, 0, stream>>>(src, dst, deg_out_a, cnt, adj);
    k_gemm1 <<<NRB2 * KSPLIT, 256, 0, stream>>>(X, W1, hpart);
    k_reduce<<<(N_NODES * 4 + 255) / 256, 256, 0, stream>>>(hpart, deg_out_a, h);
    k_layer1<<<(N_NODES + 3) / 4, 256, 0, stream>>>(h, adj, cnt, deg_out_a,
                                                    W2, b1, g);
    k_layer2<<<(N_NODES + 3) / 4, 256, 0, stream>>>(g, adj, cnt, b2, out);
}